// Round 1
// baseline (3374.408 us; speedup 1.0000x reference)
//
#include <hip/hip_runtime.h>
#include <math.h>

#define N_NODES 100000
#define N_EDGES 1600000
#define F_IN 512
#define F_GNN 128
#define HID 64
#define Z_DIM 64
#define N_GRAPHS 512

// ---------- small device helpers ----------
__device__ __forceinline__ float eluf(float v) { return v > 0.f ? v : expm1f(v); }
__device__ __forceinline__ float softplusf(float v) {
  return fmaxf(v, 0.f) + log1pf(expf(-fabsf(v)));
}
__device__ __forceinline__ float sigmoidf(float v) { return 1.f / (1.f + expf(-v)); }

__device__ __forceinline__ int lower_bound_i(const int* __restrict__ a, int n, int v) {
  int lo = 0, hi = n;
  while (lo < hi) {
    int mid = (lo + hi) >> 1;
    if (a[mid] < v) lo = mid + 1; else hi = mid;
  }
  return lo;
}

// ---------- kernel 1: init degrees (self-loop = 1) ----------
__global__ void k_init_deg(float* __restrict__ deg) {
  int i = blockIdx.x * 256 + threadIdx.x;
  if (i < N_NODES) deg[i] = 1.0f;
}

// ---------- kernel 2: in-degree accumulation ----------
__global__ void k_deg(const int* __restrict__ ei, float* __restrict__ deg) {
  int e = blockIdx.x * 256 + threadIdx.x;
  if (e < N_EDGES) atomicAdd(&deg[ei[N_EDGES + e]], 1.0f);
}

// ---------- kernel 3: sxw = (x @ Wg) * rsqrt(deg[row]); acc seeded with sxw ----------
// Tile: M=64 rows, N=128 cols (full), K-step=32. 256 threads: 16x16 grid,
// each thread computes a 4(row) x 8(col) microtile.
__global__ __launch_bounds__(256) void k_gemm(
    const float* __restrict__ x, const float* __restrict__ Wg,
    const float* __restrict__ deg,
    float* __restrict__ sxw, float* __restrict__ acc) {
  // As[m][k], pad 41 so strided scalar reads spread banks (41*4 per row)
  __shared__ float As[64][41];
  // Ws[k][n], pad 132 (528 B rows, 16B-aligned for float4 reads)
  __shared__ float Ws[32][132];

  const int t = threadIdx.x;
  const int tm = t & 15;        // 0..15 -> rows tm*4 .. tm*4+3
  const int tn = t >> 4;        // 0..15 -> cols tn*8 .. tn*8+7
  const int row0 = blockIdx.x * 64;

  float av[4][8];
#pragma unroll
  for (int j = 0; j < 4; j++)
#pragma unroll
    for (int n = 0; n < 8; n++) av[j][n] = 0.f;

#pragma unroll 1
  for (int k0 = 0; k0 < F_IN; k0 += 32) {
    // global loads (before barrier, overlap with previous compute)
    float4 ga[2];
#pragma unroll
    for (int i = 0; i < 2; i++) {
      int f = t + 256 * i;            // 0..511 float4s, coalesced
      int r = f >> 3, c4 = f & 7;     // 8 float4 per 32-wide row
      int gr = row0 + r;
      if (gr >= N_NODES) gr = N_NODES - 1;
      ga[i] = *(const float4*)&x[(size_t)gr * F_IN + k0 + c4 * 4];
    }
    float4 gw[4];
#pragma unroll
    for (int i = 0; i < 4; i++) {
      int f = t + 256 * i;            // 0..1023 float4s
      int r = f >> 5, c4 = f & 31;    // 32 float4 per 128-wide row
      gw[i] = *(const float4*)&Wg[(k0 + r) * F_GNN + c4 * 4];
    }
    __syncthreads();
#pragma unroll
    for (int i = 0; i < 2; i++) {
      int f = t + 256 * i;
      int r = f >> 3, c4 = f & 7;
      As[r][c4 * 4 + 0] = ga[i].x;
      As[r][c4 * 4 + 1] = ga[i].y;
      As[r][c4 * 4 + 2] = ga[i].z;
      As[r][c4 * 4 + 3] = ga[i].w;
    }
#pragma unroll
    for (int i = 0; i < 4; i++) {
      int f = t + 256 * i;
      int r = f >> 5, c4 = f & 31;
      *(float4*)&Ws[r][c4 * 4] = gw[i];
    }
    __syncthreads();
#pragma unroll
    for (int kk = 0; kk < 32; kk++) {
      float w[8];
      *(float4*)&w[0] = *(const float4*)&Ws[kk][tn * 8];
      *(float4*)&w[4] = *(const float4*)&Ws[kk][tn * 8 + 4];
      float a[4];
#pragma unroll
      for (int j = 0; j < 4; j++) a[j] = As[tm * 4 + j][kk];
#pragma unroll
      for (int j = 0; j < 4; j++)
#pragma unroll
        for (int n = 0; n < 8; n++) av[j][n] = fmaf(a[j], w[n], av[j][n]);
    }
  }

  // epilogue: scale by rsqrt(deg), write sxw and seed acc (self-loop term)
#pragma unroll
  for (int j = 0; j < 4; j++) {
    int gr = row0 + tm * 4 + j;
    if (gr < N_NODES) {
      float s = rsqrtf(deg[gr]);
      float4 o0 = make_float4(av[j][0] * s, av[j][1] * s, av[j][2] * s, av[j][3] * s);
      float4 o1 = make_float4(av[j][4] * s, av[j][5] * s, av[j][6] * s, av[j][7] * s);
      size_t base = (size_t)gr * F_GNN + tn * 8;
      *(float4*)&sxw[base] = o0;
      *(float4*)&sxw[base + 4] = o1;
      *(float4*)&acc[base] = o0;
      *(float4*)&acc[base + 4] = o1;
    }
  }
}

// ---------- kernel 4: edge scatter acc[dst] += sxw[src] ----------
// 32 threads per edge, float4 gather + 4 scalar atomics each.
__global__ __launch_bounds__(256) void k_scatter(
    const int* __restrict__ ei, const float* __restrict__ sxw,
    float* __restrict__ acc) {
  long long tid = (long long)blockIdx.x * 256 + threadIdx.x;
  int e = (int)(tid >> 5);
  if (e >= N_EDGES) return;
  int l = (int)(tid & 31);
  int s = ei[e];
  int d = ei[N_EDGES + e];
  float4 v = ((const float4*)sxw)[(size_t)s * 32 + l];
  float* ap = acc + (size_t)d * F_GNN + l * 4;
  atomicAdd(ap + 0, v.x);
  atomicAdd(ap + 1, v.y);
  atomicAdd(ap + 2, v.z);
  atomicAdd(ap + 3, v.w);
}

// ---------- kernel 5: finalize node_x + mean/max pool per graph ----------
__global__ __launch_bounds__(128) void k_pool(
    const float* __restrict__ acc, const float* __restrict__ deg,
    const float* __restrict__ bg, const int* __restrict__ batch,
    float* __restrict__ gx) {
  int g = blockIdx.x;
  int f = threadIdx.x;
  int start = lower_bound_i(batch, N_NODES, g);
  int end = lower_bound_i(batch, N_NODES, g + 1);
  float b = bg[f];
  float sum = 0.f, mx = 0.f;
  for (int i = start; i < end; i++) {
    float v = fmaf(acc[(size_t)i * F_GNN + f], rsqrtf(deg[i]), b);
    v = fmaxf(v, 0.f);   // relu
    sum += v;
    mx = fmaxf(mx, v);
  }
  float cnt = (float)(end - start);
  gx[g * 256 + f] = sum / fmaxf(cnt, 1.0f);
  gx[g * 256 + 128 + f] = mx;
}

// ---------- kernel 6: encoder MLP + reparam + decoder MLP ----------
__global__ __launch_bounds__(64) void k_mlp(
    const float* __restrict__ gx, const float* __restrict__ eps,
    const float* __restrict__ We1, const float* __restrict__ be1,
    const float* __restrict__ We2, const float* __restrict__ be2,
    const float* __restrict__ We3, const float* __restrict__ be3,
    const float* __restrict__ Wd1, const float* __restrict__ bd1,
    const float* __restrict__ Wd2, const float* __restrict__ bd2,
    const float* __restrict__ Wd3, const float* __restrict__ bd3,
    float* __restrict__ out) {
  __shared__ float row[256];
  __shared__ float t1[64], t2[64], zz[64], d1[64], d2[64];
  int g = blockIdx.x;
  int j = threadIdx.x;

#pragma unroll
  for (int i = 0; i < 4; i++) row[j + 64 * i] = gx[g * 256 + j + 64 * i];
  __syncthreads();

  float s = be1[j];
#pragma unroll 4
  for (int k = 0; k < 256; k++) s = fmaf(row[k], We1[k * 64 + j], s);
  t1[j] = eluf(s);
  __syncthreads();

  s = be2[j];
#pragma unroll 4
  for (int k = 0; k < 64; k++) s = fmaf(t1[k], We2[k * 64 + j], s);
  t2[j] = tanhf(s);
  __syncthreads();

  float m = be3[j], lv = be3[64 + j];
#pragma unroll 4
  for (int k = 0; k < 64; k++) {
    float tv = t2[k];
    m = fmaf(tv, We3[k * 128 + j], m);
    lv = fmaf(tv, We3[k * 128 + 64 + j], lv);
  }
  float sd = 1e-6f + softplusf(lv);
  float z = fmaf(eps[g * 64 + j], sd, m);
  out[g * 64 + j] = m;                  // mu
  out[32768 + g * 64 + j] = sd;         // stddev
  zz[j] = z;
  __syncthreads();

  s = bd1[j];
#pragma unroll 4
  for (int k = 0; k < 64; k++) s = fmaf(zz[k], Wd1[k * 64 + j], s);
  d1[j] = tanhf(s);
  __syncthreads();

  s = bd2[j];
#pragma unroll 4
  for (int k = 0; k < 64; k++) s = fmaf(d1[k], Wd2[k * 64 + j], s);
  d2[j] = eluf(s);
  __syncthreads();

  float y0 = bd3[j], y1 = bd3[64 + j];
#pragma unroll 4
  for (int k = 0; k < 64; k++) {
    float dv = d2[k];
    y0 = fmaf(dv, Wd3[k * 128 + j], y0);
    y1 = fmaf(dv, Wd3[k * 128 + 64 + j], y1);
  }
  y0 = fminf(fmaxf(sigmoidf(y0), 1e-8f), 1.f - 1e-8f);
  y1 = fminf(fmaxf(sigmoidf(y1), 1e-8f), 1.f - 1e-8f);
  out[65536 + g * 128 + j] = y0;
  out[65536 + g * 128 + 64 + j] = y1;
}

extern "C" void kernel_launch(void* const* d_in, const int* in_sizes, int n_in,
                              void* d_out, int out_size, void* d_ws, size_t ws_size,
                              hipStream_t stream) {
  const float* x     = (const float*)d_in[0];
  const int*   ei    = (const int*)d_in[1];
  const int*   batch = (const int*)d_in[2];
  const float* eps   = (const float*)d_in[3];
  const float* Wg    = (const float*)d_in[4];
  const float* bg    = (const float*)d_in[5];
  const float* We1   = (const float*)d_in[6];
  const float* be1   = (const float*)d_in[7];
  const float* We2   = (const float*)d_in[8];
  const float* be2   = (const float*)d_in[9];
  const float* We3   = (const float*)d_in[10];
  const float* be3   = (const float*)d_in[11];
  const float* Wd1   = (const float*)d_in[12];
  const float* bd1   = (const float*)d_in[13];
  const float* Wd2   = (const float*)d_in[14];
  const float* bd2   = (const float*)d_in[15];
  const float* Wd3   = (const float*)d_in[16];
  const float* bd3   = (const float*)d_in[17];
  float* out = (float*)d_out;

  float* ws  = (float*)d_ws;
  float* deg = ws;                      // 100000 (padded to 102400)
  float* sxw = ws + 102400;             // 12,800,000
  float* acc = sxw + 12800000;          // 12,800,000
  float* gx  = acc + 12800000;          // 131072

  k_init_deg<<<(N_NODES + 255) / 256, 256, 0, stream>>>(deg);
  k_deg<<<(N_EDGES + 255) / 256, 256, 0, stream>>>(ei, deg);
  k_gemm<<<(N_NODES + 63) / 64, 256, 0, stream>>>(x, Wg, deg, sxw, acc);
  {
    long long thr = (long long)N_EDGES * 32;
    int blocks = (int)((thr + 255) / 256);
    k_scatter<<<blocks, 256, 0, stream>>>(ei, sxw, acc);
  }
  k_pool<<<N_GRAPHS, 128, 0, stream>>>(acc, deg, bg, batch, gx);
  k_mlp<<<N_GRAPHS, 64, 0, stream>>>(gx, eps, We1, be1, We2, be2, We3, be3,
                                     Wd1, bd1, Wd2, bd2, Wd3, bd3, out);
}

// Round 2
// 923.322 us; speedup vs baseline: 3.6546x; 3.6546x over previous
//
#include <hip/hip_runtime.h>
#include <math.h>

#define N_NODES 100000
#define N_EDGES 1600000
#define F_IN 512
#define F_GNN 128
#define HID 64
#define Z_DIM 64
#define N_GRAPHS 512

// ---------- small device helpers ----------
__device__ __forceinline__ float eluf(float v) { return v > 0.f ? v : expm1f(v); }
__device__ __forceinline__ float softplusf(float v) {
  return fmaxf(v, 0.f) + log1pf(expf(-fabsf(v)));
}
__device__ __forceinline__ float sigmoidf(float v) { return 1.f / (1.f + expf(-v)); }

__device__ __forceinline__ int lower_bound_i(const int* __restrict__ a, int n, int v) {
  int lo = 0, hi = n;
  while (lo < hi) {
    int mid = (lo + hi) >> 1;
    if (a[mid] < v) lo = mid + 1; else hi = mid;
  }
  return lo;
}

// ---------- CSR build ----------
__global__ void k_zero(int* __restrict__ hist) {
  int i = blockIdx.x * 256 + threadIdx.x;
  if (i < N_NODES) hist[i] = 0;
}

__global__ void k_hist(const int* __restrict__ ei, int* __restrict__ hist) {
  int e = blockIdx.x * 256 + threadIdx.x;
  if (e < N_EDGES) atomicAdd(&hist[ei[N_EDGES + e]], 1);
}

// block-local exclusive scan of 512 elements per block (256 threads, 2 elems each)
__global__ __launch_bounds__(256) void k_scan1(const int* __restrict__ hist,
                                               int* __restrict__ off,
                                               int* __restrict__ bsum) {
  __shared__ int s[256];
  int b = blockIdx.x, t = threadIdx.x;
  int i0 = b * 512 + 2 * t;
  int a0 = (i0 < N_NODES) ? hist[i0] : 0;
  int a1 = (i0 + 1 < N_NODES) ? hist[i0 + 1] : 0;
  s[t] = a0 + a1;
  __syncthreads();
#pragma unroll
  for (int d = 1; d < 256; d <<= 1) {
    int v = (t >= d) ? s[t - d] : 0;
    __syncthreads();
    s[t] += v;
    __syncthreads();
  }
  int excl = (t > 0) ? s[t - 1] : 0;
  if (i0 < N_NODES) off[i0] = excl;
  if (i0 + 1 < N_NODES) off[i0 + 1] = excl + a0;
  if (t == 255) bsum[b] = s[255];
}

// exclusive scan of 196 block sums (single block)
__global__ __launch_bounds__(256) void k_scan2(const int* __restrict__ bsum,
                                               int* __restrict__ boff) {
  __shared__ int s[256];
  int t = threadIdx.x;
  s[t] = (t < 196) ? bsum[t] : 0;
  __syncthreads();
#pragma unroll
  for (int d = 1; d < 256; d <<= 1) {
    int v = (t >= d) ? s[t - d] : 0;
    __syncthreads();
    s[t] += v;
    __syncthreads();
  }
  boff[t] = (t > 0) ? s[t - 1] : 0;
}

// off += block offset; cursor = off; dinv = rsqrt(1+indeg); off[N] = E
__global__ void k_scan3(int* __restrict__ off, const int* __restrict__ boff,
                        int* __restrict__ cursor, const int* __restrict__ hist,
                        float* __restrict__ dinv) {
  int i = blockIdx.x * 256 + threadIdx.x;
  if (i < N_NODES) {
    int o = off[i] + boff[i >> 9];
    off[i] = o;
    cursor[i] = o;
    dinv[i] = rsqrtf(1.0f + (float)hist[i]);
  }
  if (i == 0) off[N_NODES] = N_EDGES;
}

__global__ void k_csr(const int* __restrict__ ei, int* __restrict__ cursor,
                      int* __restrict__ csr_src) {
  int e = blockIdx.x * 256 + threadIdx.x;
  if (e < N_EDGES) {
    int d = ei[N_EDGES + e];
    int pos = atomicAdd(&cursor[d], 1);
    csr_src[pos] = ei[e];
  }
}

// ---------- GEMM: sxw = (x @ Wg) * dinv[row] ----------
__global__ __launch_bounds__(256) void k_gemm(
    const float* __restrict__ x, const float* __restrict__ Wg,
    const float* __restrict__ dinv, float* __restrict__ sxw) {
  __shared__ float As[64][41];
  __shared__ float Ws[32][132];

  const int t = threadIdx.x;
  const int tm = t & 15;
  const int tn = t >> 4;
  const int row0 = blockIdx.x * 64;

  float av[4][8];
#pragma unroll
  for (int j = 0; j < 4; j++)
#pragma unroll
    for (int n = 0; n < 8; n++) av[j][n] = 0.f;

#pragma unroll 1
  for (int k0 = 0; k0 < F_IN; k0 += 32) {
    float4 ga[2];
#pragma unroll
    for (int i = 0; i < 2; i++) {
      int f = t + 256 * i;
      int r = f >> 3, c4 = f & 7;
      int gr = row0 + r;
      if (gr >= N_NODES) gr = N_NODES - 1;
      ga[i] = *(const float4*)&x[(size_t)gr * F_IN + k0 + c4 * 4];
    }
    float4 gw[4];
#pragma unroll
    for (int i = 0; i < 4; i++) {
      int f = t + 256 * i;
      int r = f >> 5, c4 = f & 31;
      gw[i] = *(const float4*)&Wg[(k0 + r) * F_GNN + c4 * 4];
    }
    __syncthreads();
#pragma unroll
    for (int i = 0; i < 2; i++) {
      int f = t + 256 * i;
      int r = f >> 3, c4 = f & 7;
      As[r][c4 * 4 + 0] = ga[i].x;
      As[r][c4 * 4 + 1] = ga[i].y;
      As[r][c4 * 4 + 2] = ga[i].z;
      As[r][c4 * 4 + 3] = ga[i].w;
    }
#pragma unroll
    for (int i = 0; i < 4; i++) {
      int f = t + 256 * i;
      int r = f >> 5, c4 = f & 31;
      *(float4*)&Ws[r][c4 * 4] = gw[i];
    }
    __syncthreads();
#pragma unroll
    for (int kk = 0; kk < 32; kk++) {
      float w[8];
      *(float4*)&w[0] = *(const float4*)&Ws[kk][tn * 8];
      *(float4*)&w[4] = *(const float4*)&Ws[kk][tn * 8 + 4];
      float a[4];
#pragma unroll
      for (int j = 0; j < 4; j++) a[j] = As[tm * 4 + j][kk];
#pragma unroll
      for (int j = 0; j < 4; j++)
#pragma unroll
        for (int n = 0; n < 8; n++) av[j][n] = fmaf(a[j], w[n], av[j][n]);
    }
  }

#pragma unroll
  for (int j = 0; j < 4; j++) {
    int gr = row0 + tm * 4 + j;
    if (gr < N_NODES) {
      float s = dinv[gr];
      float4 o0 = make_float4(av[j][0] * s, av[j][1] * s, av[j][2] * s, av[j][3] * s);
      float4 o1 = make_float4(av[j][4] * s, av[j][5] * s, av[j][6] * s, av[j][7] * s);
      size_t base = (size_t)gr * F_GNN + tn * 8;
      *(float4*)&sxw[base] = o0;
      *(float4*)&sxw[base + 4] = o1;
    }
  }
}

// ---------- aggregate by gather: one wave per dst node ----------
// node_x[d] = relu(dinv[d] * (sxw[d] + sum_{src in N(d)} sxw[src]) + bg)
__global__ __launch_bounds__(256) void k_agg(
    const float* __restrict__ sxw, const int* __restrict__ off,
    const int* __restrict__ csr_src, const float* __restrict__ dinv,
    const float* __restrict__ bg, float* __restrict__ node_x) {
  int node = blockIdx.x * 4 + (threadIdx.x >> 6);
  int lane = threadIdx.x & 63;
  if (node >= N_NODES) return;
  const float2* S = (const float2*)sxw;
  float2 sum = S[(size_t)node * 64 + lane];  // self-loop term
  int e = off[node];
  int e1 = off[node + 1];
  for (; e + 1 < e1; e += 2) {
    int s0 = csr_src[e];
    int s1 = csr_src[e + 1];
    float2 v0 = S[(size_t)s0 * 64 + lane];
    float2 v1 = S[(size_t)s1 * 64 + lane];
    sum.x += v0.x + v1.x;
    sum.y += v0.y + v1.y;
  }
  if (e < e1) {
    int s0 = csr_src[e];
    float2 v0 = S[(size_t)s0 * 64 + lane];
    sum.x += v0.x;
    sum.y += v0.y;
  }
  float di = dinv[node];
  float2 b = ((const float2*)bg)[lane];
  float2 r;
  r.x = fmaxf(fmaf(sum.x, di, b.x), 0.f);
  r.y = fmaxf(fmaf(sum.y, di, b.y), 0.f);
  ((float2*)node_x)[(size_t)node * 64 + lane] = r;
}

// ---------- pool: mean/max per graph ----------
__global__ __launch_bounds__(128) void k_pool(
    const float* __restrict__ node_x, const int* __restrict__ batch,
    float* __restrict__ gx) {
  int g = blockIdx.x;
  int f = threadIdx.x;
  int start = lower_bound_i(batch, N_NODES, g);
  int end = lower_bound_i(batch, N_NODES, g + 1);
  float sum = 0.f, mx = 0.f;
  for (int i = start; i < end; i++) {
    float v = node_x[(size_t)i * F_GNN + f];
    sum += v;
    mx = fmaxf(mx, v);
  }
  float cnt = (float)(end - start);
  gx[g * 256 + f] = sum / fmaxf(cnt, 1.0f);
  gx[g * 256 + 128 + f] = mx;
}

// ---------- encoder MLP + reparam + decoder MLP ----------
__global__ __launch_bounds__(64) void k_mlp(
    const float* __restrict__ gx, const float* __restrict__ eps,
    const float* __restrict__ We1, const float* __restrict__ be1,
    const float* __restrict__ We2, const float* __restrict__ be2,
    const float* __restrict__ We3, const float* __restrict__ be3,
    const float* __restrict__ Wd1, const float* __restrict__ bd1,
    const float* __restrict__ Wd2, const float* __restrict__ bd2,
    const float* __restrict__ Wd3, const float* __restrict__ bd3,
    float* __restrict__ out) {
  __shared__ float row[256];
  __shared__ float t1[64], t2[64], zz[64], d1[64], d2[64];
  int g = blockIdx.x;
  int j = threadIdx.x;

#pragma unroll
  for (int i = 0; i < 4; i++) row[j + 64 * i] = gx[g * 256 + j + 64 * i];
  __syncthreads();

  float s = be1[j];
#pragma unroll 4
  for (int k = 0; k < 256; k++) s = fmaf(row[k], We1[k * 64 + j], s);
  t1[j] = eluf(s);
  __syncthreads();

  s = be2[j];
#pragma unroll 4
  for (int k = 0; k < 64; k++) s = fmaf(t1[k], We2[k * 64 + j], s);
  t2[j] = tanhf(s);
  __syncthreads();

  float m = be3[j], lv = be3[64 + j];
#pragma unroll 4
  for (int k = 0; k < 64; k++) {
    float tv = t2[k];
    m = fmaf(tv, We3[k * 128 + j], m);
    lv = fmaf(tv, We3[k * 128 + 64 + j], lv);
  }
  float sd = 1e-6f + softplusf(lv);
  float z = fmaf(eps[g * 64 + j], sd, m);
  out[g * 64 + j] = m;                  // mu
  out[32768 + g * 64 + j] = sd;         // stddev
  zz[j] = z;
  __syncthreads();

  s = bd1[j];
#pragma unroll 4
  for (int k = 0; k < 64; k++) s = fmaf(zz[k], Wd1[k * 64 + j], s);
  d1[j] = tanhf(s);
  __syncthreads();

  s = bd2[j];
#pragma unroll 4
  for (int k = 0; k < 64; k++) s = fmaf(d1[k], Wd2[k * 64 + j], s);
  d2[j] = eluf(s);
  __syncthreads();

  float y0 = bd3[j], y1 = bd3[64 + j];
#pragma unroll 4
  for (int k = 0; k < 64; k++) {
    float dv = d2[k];
    y0 = fmaf(dv, Wd3[k * 128 + j], y0);
    y1 = fmaf(dv, Wd3[k * 128 + 64 + j], y1);
  }
  y0 = fminf(fmaxf(sigmoidf(y0), 1e-8f), 1.f - 1e-8f);
  y1 = fminf(fmaxf(sigmoidf(y1), 1e-8f), 1.f - 1e-8f);
  out[65536 + g * 128 + j] = y0;
  out[65536 + g * 128 + 64 + j] = y1;
}

extern "C" void kernel_launch(void* const* d_in, const int* in_sizes, int n_in,
                              void* d_out, int out_size, void* d_ws, size_t ws_size,
                              hipStream_t stream) {
  const float* x     = (const float*)d_in[0];
  const int*   ei    = (const int*)d_in[1];
  const int*   batch = (const int*)d_in[2];
  const float* eps   = (const float*)d_in[3];
  const float* Wg    = (const float*)d_in[4];
  const float* bg    = (const float*)d_in[5];
  const float* We1   = (const float*)d_in[6];
  const float* be1   = (const float*)d_in[7];
  const float* We2   = (const float*)d_in[8];
  const float* be2   = (const float*)d_in[9];
  const float* We3   = (const float*)d_in[10];
  const float* be3   = (const float*)d_in[11];
  const float* Wd1   = (const float*)d_in[12];
  const float* bd1   = (const float*)d_in[13];
  const float* Wd2   = (const float*)d_in[14];
  const float* bd2   = (const float*)d_in[15];
  const float* Wd3   = (const float*)d_in[16];
  const float* bd3   = (const float*)d_in[17];
  float* out = (float*)d_out;

  // workspace layout (element offsets, 4B each)
  int*   hist    = (int*)d_ws;                 // 0      .. 102399
  int*   off     = hist + 102400;              // 102400 .. 204799 (uses 100001)
  int*   cursor  = off + 102400;               // 204800 .. 307199
  float* dinv    = (float*)(cursor + 102400);  // 307200 .. 409599
  int*   bsum    = (int*)(dinv + 102400);      // 409600 .. 409855
  int*   boff    = bsum + 256;                 // 409856 .. 410111
  int*   csr_src = boff + 256;                 // 410112 .. 2010111
  float* sxw     = (float*)(csr_src + 1600000);// 2010112 .. 14810111
  float* node_x  = sxw + 12800000;             // 14810112 .. 27610111
  float* gx      = (float*)d_ws;               // overlay hist+off (free after k_agg)

  k_zero<<<(N_NODES + 255) / 256, 256, 0, stream>>>(hist);
  k_hist<<<(N_EDGES + 255) / 256, 256, 0, stream>>>(ei, hist);
  k_scan1<<<(N_NODES + 511) / 512, 256, 0, stream>>>(hist, off, bsum);
  k_scan2<<<1, 256, 0, stream>>>(bsum, boff);
  k_scan3<<<(N_NODES + 255) / 256, 256, 0, stream>>>(off, boff, cursor, hist, dinv);
  k_csr<<<(N_EDGES + 255) / 256, 256, 0, stream>>>(ei, cursor, csr_src);
  k_gemm<<<(N_NODES + 63) / 64, 256, 0, stream>>>(x, Wg, dinv, sxw);
  k_agg<<<(N_NODES + 3) / 4, 256, 0, stream>>>(sxw, off, csr_src, dinv, bg, node_x);
  k_pool<<<N_GRAPHS, 128, 0, stream>>>(node_x, batch, gx);
  k_mlp<<<N_GRAPHS, 64, 0, stream>>>(gx, eps, We1, be1, We2, be2, We3, be3,
                                     Wd1, bd1, Wd2, bd2, Wd3, bd3, out);
}

// Round 3
// 697.386 us; speedup vs baseline: 4.8386x; 1.3240x over previous
//
#include <hip/hip_runtime.h>
#include <math.h>

#define N_NODES 100000
#define N_EDGES 1600000
#define F_IN 512
#define F_GNN 128
#define HID 64
#define Z_DIM 64
#define N_GRAPHS 512

typedef __attribute__((ext_vector_type(8))) short short8;
typedef __attribute__((ext_vector_type(4))) float f32x4;

// ---------- small device helpers ----------
__device__ __forceinline__ float eluf(float v) { return v > 0.f ? v : expm1f(v); }
__device__ __forceinline__ float softplusf(float v) {
  return fmaxf(v, 0.f) + log1pf(expf(-fabsf(v)));
}
__device__ __forceinline__ float sigmoidf(float v) { return 1.f / (1.f + expf(-v)); }

__device__ __forceinline__ unsigned short f2bf(float f) {
  unsigned int u = __float_as_uint(f);
  u = (u + 0x7fffu + ((u >> 16) & 1u)) >> 16;
  return (unsigned short)u;
}
__device__ __forceinline__ float bf_lo(unsigned int u) { return __uint_as_float(u << 16); }
__device__ __forceinline__ float bf_hi(unsigned int u) { return __uint_as_float(u & 0xffff0000u); }

__device__ __forceinline__ int lower_bound_i(const int* __restrict__ a, int n, int v) {
  int lo = 0, hi = n;
  while (lo < hi) {
    int mid = (lo + hi) >> 1;
    if (a[mid] < v) lo = mid + 1; else hi = mid;
  }
  return lo;
}

// ---------- CSR build ----------
__global__ void k_zero(int* __restrict__ hist) {
  int i = blockIdx.x * 256 + threadIdx.x;
  if (i < N_NODES) hist[i] = 0;
}

__global__ void k_hist(const int* __restrict__ ei, int* __restrict__ hist) {
  int e = blockIdx.x * 256 + threadIdx.x;
  if (e < N_EDGES) atomicAdd(&hist[ei[N_EDGES + e]], 1);
}

__global__ __launch_bounds__(256) void k_scan1(const int* __restrict__ hist,
                                               int* __restrict__ off,
                                               int* __restrict__ bsum) {
  __shared__ int s[256];
  int b = blockIdx.x, t = threadIdx.x;
  int i0 = b * 512 + 2 * t;
  int a0 = (i0 < N_NODES) ? hist[i0] : 0;
  int a1 = (i0 + 1 < N_NODES) ? hist[i0 + 1] : 0;
  s[t] = a0 + a1;
  __syncthreads();
#pragma unroll
  for (int d = 1; d < 256; d <<= 1) {
    int v = (t >= d) ? s[t - d] : 0;
    __syncthreads();
    s[t] += v;
    __syncthreads();
  }
  int excl = (t > 0) ? s[t - 1] : 0;
  if (i0 < N_NODES) off[i0] = excl;
  if (i0 + 1 < N_NODES) off[i0 + 1] = excl + a0;
  if (t == 255) bsum[b] = s[255];
}

__global__ __launch_bounds__(256) void k_scan2(const int* __restrict__ bsum,
                                               int* __restrict__ boff) {
  __shared__ int s[256];
  int t = threadIdx.x;
  s[t] = (t < 196) ? bsum[t] : 0;
  __syncthreads();
#pragma unroll
  for (int d = 1; d < 256; d <<= 1) {
    int v = (t >= d) ? s[t - d] : 0;
    __syncthreads();
    s[t] += v;
    __syncthreads();
  }
  boff[t] = (t > 0) ? s[t - 1] : 0;
}

__global__ void k_scan3(int* __restrict__ off, const int* __restrict__ boff,
                        int* __restrict__ cursor, const int* __restrict__ hist,
                        float* __restrict__ dinv) {
  int i = blockIdx.x * 256 + threadIdx.x;
  if (i < N_NODES) {
    int o = off[i] + boff[i >> 9];
    off[i] = o;
    cursor[i] = o;
    dinv[i] = rsqrtf(1.0f + (float)hist[i]);
  }
  if (i == 0) off[N_NODES] = N_EDGES;
}

__global__ void k_csr(const int* __restrict__ ei, int* __restrict__ cursor,
                      int* __restrict__ csr_src) {
  int e = blockIdx.x * 256 + threadIdx.x;
  if (e < N_EDGES) {
    int d = ei[N_EDGES + e];
    int pos = atomicAdd(&cursor[d], 1);
    csr_src[pos] = ei[e];
  }
}

// ---------- Wg -> WgT bf16 (B^T layout: [n][k]) ----------
__global__ void k_wg(const float* __restrict__ Wg, unsigned short* __restrict__ WgT) {
  int i = blockIdx.x * 256 + threadIdx.x;   // 65536 total
  int n = i >> 9, k = i & 511;
  WgT[i] = f2bf(Wg[k * F_GNN + n]);
}

// ---------- MFMA GEMM: sxw_bf16 = bf16((x @ Wg) * dinv[row]) ----------
// Block tile 128x128 (N full), BK=32, 256 threads = 4 waves, wave tile 64x64.
__global__ __launch_bounds__(256) void k_gemm(
    const float* __restrict__ x, const unsigned short* __restrict__ WgT,
    const float* __restrict__ dinv, unsigned short* __restrict__ sxw) {
  __shared__ unsigned short As[128][32];   // [m][k] bf16, 64 B rows
  __shared__ unsigned short Bs[128][32];   // [n][k] bf16 (B^T), 64 B rows

  const int t = threadIdx.x;
  const int lane15 = t & 15;
  const int quad = (t & 63) >> 4;
  const int wave = t >> 6;
  const int wm = (wave & 1) * 64;
  const int wn = (wave >> 1) * 64;
  const int row0 = blockIdx.x * 128;

  f32x4 acc[4][4];
#pragma unroll
  for (int mi = 0; mi < 4; mi++)
#pragma unroll
    for (int ni = 0; ni < 4; ni++) acc[mi][ni] = (f32x4){0.f, 0.f, 0.f, 0.f};

  float4 ga[4];
  uint4 gb[2];
  auto load_tile = [&](int k0) {
#pragma unroll
    for (int i = 0; i < 4; i++) {
      int f = t + 256 * i;            // 1024 float4 = 128 rows x 8
      int r = f >> 3, c4 = f & 7;
      int gr = row0 + r;
      if (gr >= N_NODES) gr = N_NODES - 1;
      ga[i] = *(const float4*)&x[(size_t)gr * F_IN + k0 + c4 * 4];
    }
#pragma unroll
    for (int i = 0; i < 2; i++) {
      int f = t + 256 * i;            // 512 uint4 = 128 rows x 4
      int r = f >> 2, c = f & 3;
      gb[i] = *(const uint4*)&WgT[r * F_IN + k0 + c * 8];
    }
  };

  load_tile(0);
#pragma unroll 1
  for (int kt = 0; kt < 16; kt++) {
    __syncthreads();
#pragma unroll
    for (int i = 0; i < 4; i++) {
      int f = t + 256 * i;
      int r = f >> 3, c4 = f & 7;
      ushort4 o;
      o.x = f2bf(ga[i].x); o.y = f2bf(ga[i].y);
      o.z = f2bf(ga[i].z); o.w = f2bf(ga[i].w);
      *(ushort4*)&As[r][c4 * 4] = o;
    }
#pragma unroll
    for (int i = 0; i < 2; i++) {
      int f = t + 256 * i;
      int r = f >> 2, c = f & 3;
      *(uint4*)&Bs[r][c * 8] = gb[i];
    }
    __syncthreads();
    if (kt < 15) load_tile((kt + 1) * 32);

    short8 afr[4], bfr[4];
#pragma unroll
    for (int mi = 0; mi < 4; mi++)
      afr[mi] = *(const short8*)&As[wm + mi * 16 + lane15][quad * 8];
#pragma unroll
    for (int ni = 0; ni < 4; ni++)
      bfr[ni] = *(const short8*)&Bs[wn + ni * 16 + lane15][quad * 8];
#pragma unroll
    for (int mi = 0; mi < 4; mi++)
#pragma unroll
      for (int ni = 0; ni < 4; ni++)
        // swapped operands: D[m=lane15][n=quad*4+reg] = C (not C^T)
        acc[mi][ni] = __builtin_amdgcn_mfma_f32_16x16x32_bf16(
            bfr[ni], afr[mi], acc[mi][ni], 0, 0, 0);
  }

#pragma unroll
  for (int mi = 0; mi < 4; mi++) {
    int gm = row0 + wm + mi * 16 + lane15;
    if (gm < N_NODES) {
      float s = dinv[gm];
#pragma unroll
      for (int ni = 0; ni < 4; ni++) {
        int gn = wn + ni * 16 + quad * 4;
        ushort4 o;
        o.x = f2bf(acc[mi][ni][0] * s);
        o.y = f2bf(acc[mi][ni][1] * s);
        o.z = f2bf(acc[mi][ni][2] * s);
        o.w = f2bf(acc[mi][ni][3] * s);
        *(ushort4*)&sxw[(size_t)gm * F_GNN + gn] = o;
      }
    }
  }
}

// ---------- aggregate by gather (bf16 rows): one wave per dst node ----------
__global__ __launch_bounds__(256) void k_agg(
    const unsigned short* __restrict__ sxw, const int* __restrict__ off,
    const int* __restrict__ csr_src, const float* __restrict__ dinv,
    const float* __restrict__ bg, float* __restrict__ node_x) {
  int node = blockIdx.x * 4 + (threadIdx.x >> 6);
  int lane = threadIdx.x & 63;
  if (node >= N_NODES) return;
  const unsigned int* S = (const unsigned int*)sxw;  // 2 bf16 per uint, 64/row
  unsigned int u = S[(size_t)node * 64 + lane];      // self-loop term
  float sx = bf_lo(u), sy = bf_hi(u);
  int e = off[node];
  int e1 = off[node + 1];
  for (; e + 3 < e1; e += 4) {
    int s0 = csr_src[e], s1 = csr_src[e + 1], s2 = csr_src[e + 2], s3 = csr_src[e + 3];
    unsigned int v0 = S[(size_t)s0 * 64 + lane];
    unsigned int v1 = S[(size_t)s1 * 64 + lane];
    unsigned int v2 = S[(size_t)s2 * 64 + lane];
    unsigned int v3 = S[(size_t)s3 * 64 + lane];
    sx += bf_lo(v0) + bf_lo(v1) + bf_lo(v2) + bf_lo(v3);
    sy += bf_hi(v0) + bf_hi(v1) + bf_hi(v2) + bf_hi(v3);
  }
  for (; e < e1; e++) {
    unsigned int v0 = S[(size_t)csr_src[e] * 64 + lane];
    sx += bf_lo(v0);
    sy += bf_hi(v0);
  }
  float di = dinv[node];
  float2 b = ((const float2*)bg)[lane];
  float2 r;
  r.x = fmaxf(fmaf(sx, di, b.x), 0.f);
  r.y = fmaxf(fmaf(sy, di, b.y), 0.f);
  ((float2*)node_x)[(size_t)node * 64 + lane] = r;
}

// ---------- pool: mean/max per graph (512 threads, 4 rows/iter) ----------
__global__ __launch_bounds__(512) void k_pool(
    const float* __restrict__ node_x, const int* __restrict__ batch,
    float* __restrict__ gx) {
  __shared__ float ssum[4][128];
  __shared__ float smax[4][128];
  int g = blockIdx.x;
  int f = threadIdx.x & 127;
  int h = threadIdx.x >> 7;
  int start = lower_bound_i(batch, N_NODES, g);
  int end = lower_bound_i(batch, N_NODES, g + 1);
  float sum = 0.f, mx = 0.f;
  for (int i = start + h; i < end; i += 4) {
    float v = node_x[(size_t)i * F_GNN + f];
    sum += v;
    mx = fmaxf(mx, v);
  }
  ssum[h][f] = sum;
  smax[h][f] = mx;
  __syncthreads();
  if (h == 0) {
    sum = ssum[0][f] + ssum[1][f] + ssum[2][f] + ssum[3][f];
    mx = fmaxf(fmaxf(smax[0][f], smax[1][f]), fmaxf(smax[2][f], smax[3][f]));
    float cnt = (float)(end - start);
    gx[g * 256 + f] = sum / fmaxf(cnt, 1.0f);
    gx[g * 256 + 128 + f] = mx;
  }
}

// ---------- encoder MLP + reparam + decoder MLP ----------
__global__ __launch_bounds__(64) void k_mlp(
    const float* __restrict__ gx, const float* __restrict__ eps,
    const float* __restrict__ We1, const float* __restrict__ be1,
    const float* __restrict__ We2, const float* __restrict__ be2,
    const float* __restrict__ We3, const float* __restrict__ be3,
    const float* __restrict__ Wd1, const float* __restrict__ bd1,
    const float* __restrict__ Wd2, const float* __restrict__ bd2,
    const float* __restrict__ Wd3, const float* __restrict__ bd3,
    float* __restrict__ out) {
  __shared__ float row[256];
  __shared__ float t1[64], t2[64], zz[64], d1[64], d2[64];
  int g = blockIdx.x;
  int j = threadIdx.x;

#pragma unroll
  for (int i = 0; i < 4; i++) row[j + 64 * i] = gx[g * 256 + j + 64 * i];
  __syncthreads();

  float s = be1[j];
#pragma unroll 4
  for (int k = 0; k < 256; k++) s = fmaf(row[k], We1[k * 64 + j], s);
  t1[j] = eluf(s);
  __syncthreads();

  s = be2[j];
#pragma unroll 4
  for (int k = 0; k < 64; k++) s = fmaf(t1[k], We2[k * 64 + j], s);
  t2[j] = tanhf(s);
  __syncthreads();

  float m = be3[j], lv = be3[64 + j];
#pragma unroll 4
  for (int k = 0; k < 64; k++) {
    float tv = t2[k];
    m = fmaf(tv, We3[k * 128 + j], m);
    lv = fmaf(tv, We3[k * 128 + 64 + j], lv);
  }
  float sd = 1e-6f + softplusf(lv);
  float z = fmaf(eps[g * 64 + j], sd, m);
  out[g * 64 + j] = m;                  // mu
  out[32768 + g * 64 + j] = sd;         // stddev
  zz[j] = z;
  __syncthreads();

  s = bd1[j];
#pragma unroll 4
  for (int k = 0; k < 64; k++) s = fmaf(zz[k], Wd1[k * 64 + j], s);
  d1[j] = tanhf(s);
  __syncthreads();

  s = bd2[j];
#pragma unroll 4
  for (int k = 0; k < 64; k++) s = fmaf(d1[k], Wd2[k * 64 + j], s);
  d2[j] = eluf(s);
  __syncthreads();

  float y0 = bd3[j], y1 = bd3[64 + j];
#pragma unroll 4
  for (int k = 0; k < 64; k++) {
    float dv = d2[k];
    y0 = fmaf(dv, Wd3[k * 128 + j], y0);
    y1 = fmaf(dv, Wd3[k * 128 + 64 + j], y1);
  }
  y0 = fminf(fmaxf(sigmoidf(y0), 1e-8f), 1.f - 1e-8f);
  y1 = fminf(fmaxf(sigmoidf(y1), 1e-8f), 1.f - 1e-8f);
  out[65536 + g * 128 + j] = y0;
  out[65536 + g * 128 + 64 + j] = y1;
}

extern "C" void kernel_launch(void* const* d_in, const int* in_sizes, int n_in,
                              void* d_out, int out_size, void* d_ws, size_t ws_size,
                              hipStream_t stream) {
  const float* x     = (const float*)d_in[0];
  const int*   ei    = (const int*)d_in[1];
  const int*   batch = (const int*)d_in[2];
  const float* eps   = (const float*)d_in[3];
  const float* Wg    = (const float*)d_in[4];
  const float* bg    = (const float*)d_in[5];
  const float* We1   = (const float*)d_in[6];
  const float* be1   = (const float*)d_in[7];
  const float* We2   = (const float*)d_in[8];
  const float* be2   = (const float*)d_in[9];
  const float* We3   = (const float*)d_in[10];
  const float* be3   = (const float*)d_in[11];
  const float* Wd1   = (const float*)d_in[12];
  const float* bd1   = (const float*)d_in[13];
  const float* Wd2   = (const float*)d_in[14];
  const float* bd2   = (const float*)d_in[15];
  const float* Wd3   = (const float*)d_in[16];
  const float* bd3   = (const float*)d_in[17];
  float* out = (float*)d_out;

  // workspace layout (4B element offsets)
  int*            hist    = (int*)d_ws;                  // 0 .. 102399
  int*            off     = hist + 102400;               // 102400 .. (100001 used)
  int*            cursor  = off + 102400;                // 204800 ..
  float*          dinv    = (float*)(cursor + 102400);   // 307200 ..
  int*            bsum    = (int*)(dinv + 102400);       // 409600 (256)
  int*            boff    = bsum + 256;                  // 409856 (256)
  int*            csr_src = boff + 256;                  // 410112 .. 2010111
  unsigned short* WgT     = (unsigned short*)(csr_src + 1600000); // 32768 uints
  unsigned short* sxw     = (unsigned short*)((int*)d_ws + 2042880); // 6.4M uints
  float*          node_x  = (float*)((int*)d_ws + 8442880);         // 12.8M floats
  float*          gx      = (float*)d_ws;  // overlay hist/off region after k_agg

  k_zero<<<(N_NODES + 255) / 256, 256, 0, stream>>>(hist);
  k_hist<<<(N_EDGES + 255) / 256, 256, 0, stream>>>(ei, hist);
  k_scan1<<<(N_NODES + 511) / 512, 256, 0, stream>>>(hist, off, bsum);
  k_scan2<<<1, 256, 0, stream>>>(bsum, boff);
  k_scan3<<<(N_NODES + 255) / 256, 256, 0, stream>>>(off, boff, cursor, hist, dinv);
  k_csr<<<(N_EDGES + 255) / 256, 256, 0, stream>>>(ei, cursor, csr_src);
  k_wg<<<(F_IN * F_GNN) / 256, 256, 0, stream>>>(Wg, WgT);
  k_gemm<<<(N_NODES + 127) / 128, 256, 0, stream>>>(x, WgT, dinv, sxw);
  k_agg<<<(N_NODES + 3) / 4, 256, 0, stream>>>(sxw, off, csr_src, dinv, bg, node_x);
  k_pool<<<N_GRAPHS, 512, 0, stream>>>(node_x, batch, gx);
  k_mlp<<<N_GRAPHS, 64, 0, stream>>>(gx, eps, We1, be1, We2, be2, We3, be3,
                                     Wd1, bd1, Wd2, bd2, Wd3, bd3, out);
}

// Round 4
// 627.465 us; speedup vs baseline: 5.3778x; 1.1114x over previous
//
#include <hip/hip_runtime.h>
#include <hip/hip_bf16.h>
#include <math.h>

#define N_NODES 100000
#define N_EDGES 1600000
#define F_IN 512
#define F_GNN 128
#define HID 64
#define Z_DIM 64
#define N_GRAPHS 512
#define N_REGIONS 196      // 512 nodes per region
#define REGION_CAP 10240   // mean 8192, sd 90 -> +22 sigma

typedef __attribute__((ext_vector_type(8))) short short8;
typedef __attribute__((ext_vector_type(4))) float f32x4;

// ---------- small device helpers ----------
__device__ __forceinline__ float eluf(float v) { return v > 0.f ? v : expm1f(v); }
__device__ __forceinline__ float softplusf(float v) {
  return fmaxf(v, 0.f) + log1pf(expf(-fabsf(v)));
}
__device__ __forceinline__ float sigmoidf(float v) { return 1.f / (1.f + expf(-v)); }

__device__ __forceinline__ unsigned short f2bf(float f) {
  unsigned int u = __float_as_uint(f);
  u = (u + 0x7fffu + ((u >> 16) & 1u)) >> 16;
  return (unsigned short)u;
}
// packed f32x2 -> bf16x2 (low = a, high = b)
__device__ __forceinline__ unsigned int f2bf2(float a, float b) {
  __hip_bfloat162 h = __float22bfloat162_rn(make_float2(a, b));
  unsigned int u;
  __builtin_memcpy(&u, &h, 4);
  return u;
}
__device__ __forceinline__ float bf_lo(unsigned int u) { return __uint_as_float(u << 16); }
__device__ __forceinline__ float bf_hi(unsigned int u) { return __uint_as_float(u & 0xffff0000u); }

__device__ __forceinline__ int lower_bound_i(const int* __restrict__ a, int n, int v) {
  int lo = 0, hi = n;
  while (lo < hi) {
    int mid = (lo + hi) >> 1;
    if (a[mid] < v) lo = mid + 1; else hi = mid;
  }
  return lo;
}

// ---------- CSR build: histogram + scan ----------
__global__ void k_zero(int* __restrict__ hist) {
  int i = blockIdx.x * 256 + threadIdx.x;
  if (i < N_NODES) hist[i] = 0;
}

__global__ void k_hist(const int* __restrict__ ei, int* __restrict__ hist) {
  int e = blockIdx.x * 256 + threadIdx.x;
  if (e < N_EDGES) atomicAdd(&hist[ei[N_EDGES + e]], 1);
}

__global__ __launch_bounds__(256) void k_scan1(const int* __restrict__ hist,
                                               int* __restrict__ off,
                                               int* __restrict__ bsum) {
  __shared__ int s[256];
  int b = blockIdx.x, t = threadIdx.x;
  int i0 = b * 512 + 2 * t;
  int a0 = (i0 < N_NODES) ? hist[i0] : 0;
  int a1 = (i0 + 1 < N_NODES) ? hist[i0 + 1] : 0;
  s[t] = a0 + a1;
  __syncthreads();
#pragma unroll
  for (int d = 1; d < 256; d <<= 1) {
    int v = (t >= d) ? s[t - d] : 0;
    __syncthreads();
    s[t] += v;
    __syncthreads();
  }
  int excl = (t > 0) ? s[t - 1] : 0;
  if (i0 < N_NODES) off[i0] = excl;
  if (i0 + 1 < N_NODES) off[i0 + 1] = excl + a0;
  if (t == 255) bsum[b] = s[255];
}

__global__ __launch_bounds__(256) void k_scan2(const int* __restrict__ bsum,
                                               int* __restrict__ boff) {
  __shared__ int s[256];
  int t = threadIdx.x;
  s[t] = (t < N_REGIONS) ? bsum[t] : 0;
  __syncthreads();
#pragma unroll
  for (int d = 1; d < 256; d <<= 1) {
    int v = (t >= d) ? s[t - d] : 0;
    __syncthreads();
    s[t] += v;
    __syncthreads();
  }
  boff[t] = (t > 0) ? s[t - 1] : 0;
}

// finalize off, dinv; seed region cursors from off[r*512]
__global__ void k_scan3(int* __restrict__ off, const int* __restrict__ boff,
                        const int* __restrict__ hist, float* __restrict__ dinv,
                        int* __restrict__ cursor_r) {
  int i = blockIdx.x * 256 + threadIdx.x;
  if (i < N_NODES) {
    int o = off[i] + boff[i >> 9];
    off[i] = o;
    dinv[i] = rsqrtf(1.0f + (float)hist[i]);
    if ((i & 511) == 0) cursor_r[i >> 9] = o;
  }
  if (i == 0) off[N_NODES] = N_EDGES;
}

// ---------- pass 1: bucket edges into 196 regions, LDS-staged ----------
__global__ __launch_bounds__(256) void k_bucket(
    const int* __restrict__ ei, int* __restrict__ cursor_r,
    uint2* __restrict__ pairs) {
  __shared__ int lhist[256];
  __shared__ int lofs[256];
  __shared__ int lcur[256];
  __shared__ int gbase[256];
  __shared__ int sc[256];
  __shared__ uint2 lpairs[4096];   // 32 KB

  const int b = blockIdx.x, t = threadIdx.x;
  const int e0 = b * 4096;
  const int n_b = min(4096, N_EDGES - e0);

  lhist[t] = 0;
  lcur[t] = 0;
  __syncthreads();

  int srcv[16], dstv[16];
#pragma unroll
  for (int j = 0; j < 16; j++) {
    int e = e0 + t + 256 * j;
    if (e < N_EDGES) {
      srcv[j] = ei[e];
      dstv[j] = ei[N_EDGES + e];
      atomicAdd(&lhist[dstv[j] >> 9], 1);
    } else {
      dstv[j] = -1;
    }
  }
  __syncthreads();

  // exclusive scan of lhist -> lofs
  sc[t] = lhist[t];
  __syncthreads();
#pragma unroll
  for (int d = 1; d < 256; d <<= 1) {
    int v = (t >= d) ? sc[t - d] : 0;
    __syncthreads();
    sc[t] += v;
    __syncthreads();
  }
  lofs[t] = (t > 0) ? sc[t - 1] : 0;
  // global base per region
  if (t < N_REGIONS && lhist[t] > 0) gbase[t] = atomicAdd(&cursor_r[t], lhist[t]);
  __syncthreads();

  // local scatter into LDS, region-contiguous
#pragma unroll
  for (int j = 0; j < 16; j++) {
    if (dstv[j] >= 0) {
      int r = dstv[j] >> 9;
      int pos = lofs[r] + atomicAdd(&lcur[r], 1);
      lpairs[pos] = make_uint2((unsigned)srcv[j], (unsigned)dstv[j]);
    }
  }
  __syncthreads();

  // flush: consecutive i -> consecutive slot within region run (coalesced)
  for (int i = t; i < n_b; i += 256) {
    int lo = 0, hi = N_REGIONS;
    while (hi - lo > 1) {
      int mid = (lo + hi) >> 1;
      if (lofs[mid] <= i) lo = mid; else hi = mid;
    }
    pairs[gbase[lo] + (i - lofs[lo])] = lpairs[i];
  }
}

// ---------- pass 2: per-region counting sort -> csr_src ----------
__global__ __launch_bounds__(256) void k_csr2(
    const uint2* __restrict__ pairs, const int* __restrict__ off,
    int* __restrict__ csr_src) {
  __shared__ int ncur[512];
  __shared__ int cbuf[REGION_CAP];   // 40 KB

  const int r = blockIdx.x, t = threadIdx.x;
  const int base = off[r << 9];
  const int endn = min((r + 1) << 9, N_NODES);
  const int end = off[endn];
  const int cnt = end - base;

  ncur[t] = 0;
  ncur[t + 256] = 0;
  __syncthreads();

  for (int i = t; i < cnt; i += 256) {
    uint2 p = pairs[base + i];
    int d = (int)p.y;
    int lpos = (off[d] - base) + atomicAdd(&ncur[d & 511], 1);
    if (lpos < REGION_CAP) cbuf[lpos] = (int)p.x;
  }
  __syncthreads();
  for (int i = t; i < cnt; i += 256) csr_src[base + i] = cbuf[i];
}

// ---------- Wg -> WgT bf16 (B^T layout: [n][k]) ----------
__global__ void k_wg(const float* __restrict__ Wg, unsigned short* __restrict__ WgT) {
  int i = blockIdx.x * 256 + threadIdx.x;   // 65536 total
  int n = i >> 9, k = i & 511;
  WgT[i] = f2bf(Wg[k * F_GNN + n]);
}

// ---------- MFMA GEMM: sxw_bf16 = bf16((x @ Wg) * dinv[row]) ----------
__global__ __launch_bounds__(256) void k_gemm(
    const float* __restrict__ x, const unsigned short* __restrict__ WgT,
    const float* __restrict__ dinv, unsigned short* __restrict__ sxw) {
  __shared__ unsigned short As[128][32];   // [m][k] bf16
  __shared__ unsigned short Bs[128][32];   // [n][k] bf16 (B^T)

  const int t = threadIdx.x;
  const int lane15 = t & 15;
  const int quad = (t & 63) >> 4;
  const int wave = t >> 6;
  const int wm = (wave & 1) * 64;
  const int wn = (wave >> 1) * 64;
  const int row0 = blockIdx.x * 128;

  f32x4 acc[4][4];
#pragma unroll
  for (int mi = 0; mi < 4; mi++)
#pragma unroll
    for (int ni = 0; ni < 4; ni++) acc[mi][ni] = (f32x4){0.f, 0.f, 0.f, 0.f};

  float4 ga[4];
  uint4 gb[2];
  auto load_tile = [&](int k0) {
#pragma unroll
    for (int i = 0; i < 4; i++) {
      int f = t + 256 * i;
      int r = f >> 3, c4 = f & 7;
      int gr = row0 + r;
      if (gr >= N_NODES) gr = N_NODES - 1;
      ga[i] = *(const float4*)&x[(size_t)gr * F_IN + k0 + c4 * 4];
    }
#pragma unroll
    for (int i = 0; i < 2; i++) {
      int f = t + 256 * i;
      int r = f >> 2, c = f & 3;
      gb[i] = *(const uint4*)&WgT[r * F_IN + k0 + c * 8];
    }
  };

  load_tile(0);
#pragma unroll 1
  for (int kt = 0; kt < 16; kt++) {
    __syncthreads();
#pragma unroll
    for (int i = 0; i < 4; i++) {
      int f = t + 256 * i;
      int r = f >> 3, c4 = f & 7;
      unsigned int u0 = f2bf2(ga[i].x, ga[i].y);
      unsigned int u1 = f2bf2(ga[i].z, ga[i].w);
      *(uint2*)&As[r][c4 * 4] = make_uint2(u0, u1);
    }
#pragma unroll
    for (int i = 0; i < 2; i++) {
      int f = t + 256 * i;
      int r = f >> 2, c = f & 3;
      *(uint4*)&Bs[r][c * 8] = gb[i];
    }
    __syncthreads();
    if (kt < 15) load_tile((kt + 1) * 32);

    short8 afr[4], bfr[4];
#pragma unroll
    for (int mi = 0; mi < 4; mi++)
      afr[mi] = *(const short8*)&As[wm + mi * 16 + lane15][quad * 8];
#pragma unroll
    for (int ni = 0; ni < 4; ni++)
      bfr[ni] = *(const short8*)&Bs[wn + ni * 16 + lane15][quad * 8];
#pragma unroll
    for (int mi = 0; mi < 4; mi++)
#pragma unroll
      for (int ni = 0; ni < 4; ni++)
        acc[mi][ni] = __builtin_amdgcn_mfma_f32_16x16x32_bf16(
            bfr[ni], afr[mi], acc[mi][ni], 0, 0, 0);
  }

#pragma unroll
  for (int mi = 0; mi < 4; mi++) {
    int gm = row0 + wm + mi * 16 + lane15;
    if (gm < N_NODES) {
      float s = dinv[gm];
#pragma unroll
      for (int ni = 0; ni < 4; ni++) {
        int gn = wn + ni * 16 + quad * 4;
        unsigned int u0 = f2bf2(acc[mi][ni][0] * s, acc[mi][ni][1] * s);
        unsigned int u1 = f2bf2(acc[mi][ni][2] * s, acc[mi][ni][3] * s);
        *(uint2*)&sxw[(size_t)gm * F_GNN + gn] = make_uint2(u0, u1);
      }
    }
  }
}

// ---------- aggregate by gather (bf16 rows): one wave per dst node ----------
__global__ __launch_bounds__(256) void k_agg(
    const unsigned short* __restrict__ sxw, const int* __restrict__ off,
    const int* __restrict__ csr_src, const float* __restrict__ dinv,
    const float* __restrict__ bg, float* __restrict__ node_x) {
  int node = blockIdx.x * 4 + (threadIdx.x >> 6);
  int lane = threadIdx.x & 63;
  if (node >= N_NODES) return;
  const unsigned int* S = (const unsigned int*)sxw;  // 2 bf16 per uint
  unsigned int u = S[(size_t)node * 64 + lane];      // self-loop
  float sx = bf_lo(u), sy = bf_hi(u);
  int e = off[node];
  int e1 = off[node + 1];
  for (; e + 7 < e1; e += 8) {
    int s0 = csr_src[e + 0], s1 = csr_src[e + 1];
    int s2 = csr_src[e + 2], s3 = csr_src[e + 3];
    int s4 = csr_src[e + 4], s5 = csr_src[e + 5];
    int s6 = csr_src[e + 6], s7 = csr_src[e + 7];
    unsigned int v0 = S[(size_t)s0 * 64 + lane];
    unsigned int v1 = S[(size_t)s1 * 64 + lane];
    unsigned int v2 = S[(size_t)s2 * 64 + lane];
    unsigned int v3 = S[(size_t)s3 * 64 + lane];
    unsigned int v4 = S[(size_t)s4 * 64 + lane];
    unsigned int v5 = S[(size_t)s5 * 64 + lane];
    unsigned int v6 = S[(size_t)s6 * 64 + lane];
    unsigned int v7 = S[(size_t)s7 * 64 + lane];
    sx += bf_lo(v0) + bf_lo(v1) + bf_lo(v2) + bf_lo(v3)
        + bf_lo(v4) + bf_lo(v5) + bf_lo(v6) + bf_lo(v7);
    sy += bf_hi(v0) + bf_hi(v1) + bf_hi(v2) + bf_hi(v3)
        + bf_hi(v4) + bf_hi(v5) + bf_hi(v6) + bf_hi(v7);
  }
  for (; e < e1; e++) {
    unsigned int v0 = S[(size_t)csr_src[e] * 64 + lane];
    sx += bf_lo(v0);
    sy += bf_hi(v0);
  }
  float di = dinv[node];
  float2 b = ((const float2*)bg)[lane];
  float2 r;
  r.x = fmaxf(fmaf(sx, di, b.x), 0.f);
  r.y = fmaxf(fmaf(sy, di, b.y), 0.f);
  ((float2*)node_x)[(size_t)node * 64 + lane] = r;
}

// ---------- pool: mean/max per graph ----------
__global__ __launch_bounds__(512) void k_pool(
    const float* __restrict__ node_x, const int* __restrict__ batch,
    float* __restrict__ gx) {
  __shared__ float ssum[4][128];
  __shared__ float smax[4][128];
  int g = blockIdx.x;
  int f = threadIdx.x & 127;
  int h = threadIdx.x >> 7;
  int start = lower_bound_i(batch, N_NODES, g);
  int end = lower_bound_i(batch, N_NODES, g + 1);
  float sum = 0.f, mx = 0.f;
  for (int i = start + h; i < end; i += 4) {
    float v = node_x[(size_t)i * F_GNN + f];
    sum += v;
    mx = fmaxf(mx, v);
  }
  ssum[h][f] = sum;
  smax[h][f] = mx;
  __syncthreads();
  if (h == 0) {
    sum = ssum[0][f] + ssum[1][f] + ssum[2][f] + ssum[3][f];
    mx = fmaxf(fmaxf(smax[0][f], smax[1][f]), fmaxf(smax[2][f], smax[3][f]));
    float cnt = (float)(end - start);
    gx[g * 256 + f] = sum / fmaxf(cnt, 1.0f);
    gx[g * 256 + 128 + f] = mx;
  }
}

// ---------- encoder MLP + reparam + decoder MLP ----------
__global__ __launch_bounds__(64) void k_mlp(
    const float* __restrict__ gx, const float* __restrict__ eps,
    const float* __restrict__ We1, const float* __restrict__ be1,
    const float* __restrict__ We2, const float* __restrict__ be2,
    const float* __restrict__ We3, const float* __restrict__ be3,
    const float* __restrict__ Wd1, const float* __restrict__ bd1,
    const float* __restrict__ Wd2, const float* __restrict__ bd2,
    const float* __restrict__ Wd3, const float* __restrict__ bd3,
    float* __restrict__ out) {
  __shared__ float row[256];
  __shared__ float t1[64], t2[64], zz[64], d1[64], d2[64];
  int g = blockIdx.x;
  int j = threadIdx.x;

#pragma unroll
  for (int i = 0; i < 4; i++) row[j + 64 * i] = gx[g * 256 + j + 64 * i];
  __syncthreads();

  float s = be1[j];
#pragma unroll 4
  for (int k = 0; k < 256; k++) s = fmaf(row[k], We1[k * 64 + j], s);
  t1[j] = eluf(s);
  __syncthreads();

  s = be2[j];
#pragma unroll 4
  for (int k = 0; k < 64; k++) s = fmaf(t1[k], We2[k * 64 + j], s);
  t2[j] = tanhf(s);
  __syncthreads();

  float m = be3[j], lv = be3[64 + j];
#pragma unroll 4
  for (int k = 0; k < 64; k++) {
    float tv = t2[k];
    m = fmaf(tv, We3[k * 128 + j], m);
    lv = fmaf(tv, We3[k * 128 + 64 + j], lv);
  }
  float sd = 1e-6f + softplusf(lv);
  float z = fmaf(eps[g * 64 + j], sd, m);
  out[g * 64 + j] = m;                  // mu
  out[32768 + g * 64 + j] = sd;         // stddev
  zz[j] = z;
  __syncthreads();

  s = bd1[j];
#pragma unroll 4
  for (int k = 0; k < 64; k++) s = fmaf(zz[k], Wd1[k * 64 + j], s);
  d1[j] = tanhf(s);
  __syncthreads();

  s = bd2[j];
#pragma unroll 4
  for (int k = 0; k < 64; k++) s = fmaf(d1[k], Wd2[k * 64 + j], s);
  d2[j] = eluf(s);
  __syncthreads();

  float y0 = bd3[j], y1 = bd3[64 + j];
#pragma unroll 4
  for (int k = 0; k < 64; k++) {
    float dv = d2[k];
    y0 = fmaf(dv, Wd3[k * 128 + j], y0);
    y1 = fmaf(dv, Wd3[k * 128 + 64 + j], y1);
  }
  y0 = fminf(fmaxf(sigmoidf(y0), 1e-8f), 1.f - 1e-8f);
  y1 = fminf(fmaxf(sigmoidf(y1), 1e-8f), 1.f - 1e-8f);
  out[65536 + g * 128 + j] = y0;
  out[65536 + g * 128 + 64 + j] = y1;
}

extern "C" void kernel_launch(void* const* d_in, const int* in_sizes, int n_in,
                              void* d_out, int out_size, void* d_ws, size_t ws_size,
                              hipStream_t stream) {
  const float* x     = (const float*)d_in[0];
  const int*   ei    = (const int*)d_in[1];
  const int*   batch = (const int*)d_in[2];
  const float* eps   = (const float*)d_in[3];
  const float* Wg    = (const float*)d_in[4];
  const float* bg    = (const float*)d_in[5];
  const float* We1   = (const float*)d_in[6];
  const float* be1   = (const float*)d_in[7];
  const float* We2   = (const float*)d_in[8];
  const float* be2   = (const float*)d_in[9];
  const float* We3   = (const float*)d_in[10];
  const float* be3   = (const float*)d_in[11];
  const float* Wd1   = (const float*)d_in[12];
  const float* bd1   = (const float*)d_in[13];
  const float* Wd2   = (const float*)d_in[14];
  const float* bd2   = (const float*)d_in[15];
  const float* Wd3   = (const float*)d_in[16];
  const float* bd3   = (const float*)d_in[17];
  float* out = (float*)d_out;

  // workspace layout (4B element offsets)
  int*            hist     = (int*)d_ws;                    // 0 (102400)
  int*            off      = hist + 102400;                 // 102400 (102528; off[N] used)
  float*          dinv     = (float*)(off + 102528);        // 204928 (102400)
  int*            bsum     = (int*)(dinv + 102400);         // 307328 (256)
  int*            boff     = bsum + 256;                    // 307584 (256)
  int*            cursor_r = boff + 256;                    // 307840 (256)
  int*            csr_src  = cursor_r + 384;                // 308224 (1,600,000)
  uint2*          pairs    = (uint2*)(csr_src + 1600000);   // 1,908,224 (3,200,000 ints, 8B-aligned)
  unsigned short* WgT      = (unsigned short*)((int*)d_ws + 5108224);  // 32768 ints
  unsigned short* sxw      = (unsigned short*)((int*)d_ws + 5140992);  // 6,400,000 ints
  float*          node_x   = (float*)((int*)d_ws + 11540992);          // 12,800,000
  float*          gx       = (float*)d_ws;  // overlays hist+off head (dead after k_agg)

  k_zero<<<(N_NODES + 255) / 256, 256, 0, stream>>>(hist);
  k_hist<<<(N_EDGES + 255) / 256, 256, 0, stream>>>(ei, hist);
  k_scan1<<<N_REGIONS, 256, 0, stream>>>(hist, off, bsum);
  k_scan2<<<1, 256, 0, stream>>>(bsum, boff);
  k_scan3<<<(N_NODES + 255) / 256, 256, 0, stream>>>(off, boff, hist, dinv, cursor_r);
  k_bucket<<<(N_EDGES + 4095) / 4096, 256, 0, stream>>>(ei, cursor_r, pairs);
  k_csr2<<<N_REGIONS, 256, 0, stream>>>(pairs, off, csr_src);
  k_wg<<<(F_IN * F_GNN) / 256, 256, 0, stream>>>(Wg, WgT);
  k_gemm<<<(N_NODES + 127) / 128, 256, 0, stream>>>(x, WgT, dinv, sxw);
  k_agg<<<(N_NODES + 3) / 4, 256, 0, stream>>>(sxw, off, csr_src, dinv, bg, node_x);
  k_pool<<<N_GRAPHS, 512, 0, stream>>>(node_x, batch, gx);
  k_mlp<<<N_GRAPHS, 64, 0, stream>>>(gx, eps, We1, be1, We2, be2, We3, be3,
                                     Wd1, bd1, Wd2, bd2, Wd3, bd3, out);
}